// Round 4
// baseline (401.301 us; speedup 1.0000x reference)
//
#include <hip/hip_runtime.h>
#include <hip/hip_bf16.h>

typedef short    short8  __attribute__((ext_vector_type(8)));
typedef unsigned uint2v  __attribute__((ext_vector_type(2)));
typedef float    f32x4   __attribute__((ext_vector_type(4)));

#define B_TOT 4096
#define SEQ   256
#define NDOF  7
#define HDIM  256
#define ROWS  16
#define DTF   0.002f

// RNE float->bf16 (setup only)
static __device__ __forceinline__ unsigned short f2bf(float f) {
    union { float f; unsigned u; } u; u.f = f;
    unsigned x = u.u;
    unsigned r = (x + 0x7FFFu + ((x >> 16) & 1u)) >> 16;
    return (unsigned short)r;
}
static __device__ __forceinline__ unsigned cvt_pk_bf16(float lo, float hi) {
    unsigned r;
    asm("v_cvt_pk_bf16_f32 %0, %1, %2" : "=v"(r) : "v"(lo), "v"(hi));
    return r;
}
static __device__ __forceinline__ float silu(float p) {
    return p * __builtin_amdgcn_rcpf(1.0f + __expf(-p));
}

__global__ __launch_bounds__(512, 2)
void NeuralODE_kernel(const float* __restrict__ st0, const float* __restrict__ tq,
                      const float* __restrict__ W1,  const float* __restrict__ b1,
                      const float* __restrict__ W2,  const float* __restrict__ b2,
                      const float* __restrict__ W3,  const float* __restrict__ b3,
                      float* __restrict__ out)
{
    __shared__ __align__(16) short h1b[16 * 264];
    __shared__ __align__(16) short h2b[16 * 264];
    __shared__ __align__(16) short xbuf[8 * 16 * 40];   // per-wave x strip: [n][40] bf16

    const int tid  = threadIdx.x;
    const int w    = tid >> 6;          // 8 waves
    const int lane = tid & 63;
    const int g    = lane >> 4;
    const int n    = lane & 15;
    const int b0   = blockIdx.x * ROWS;
    const int mb   = 32 * w;

    // ---------------- init: zero xbuf (incl. permanent-zero k24..31 region) ------
    for (int i = tid; i < 8 * 16 * 40; i += 512) xbuf[i] = 0;

    // ---------------- weight fragments (transposed GEMM; b1 folded at k==7) ------
    short8 a1f[2];
#pragma unroll
    for (int t = 0; t < 2; ++t) {
        short8 fr;
#pragma unroll
        for (int j = 0; j < 8; ++j) {
            int k = 8 * g + j;   // x: 0-6=q, 7=1(bias), 8-14=v, 15=0, 16-22=tau, 23+=0
            int m = mb + 16 * t + n;
            float v;
            if (k < 7)        v = W1[k * HDIM + m];
            else if (k == 7)  v = b1[m];
            else if (k < 15)  v = W1[(k - 1) * HDIM + m];
            else if (k == 15) v = 0.0f;
            else if (k < 23)  v = W1[(k - 2) * HDIM + m];
            else              v = 0.0f;
            fr[j] = (short)f2bf(v);
        }
        a1f[t] = fr;
    }
    short8 a2f[2][8];
#pragma unroll
    for (int t = 0; t < 2; ++t)
#pragma unroll
        for (int ks = 0; ks < 8; ++ks) {
            short8 fr;
#pragma unroll
            for (int j = 0; j < 8; ++j) {
                int k = 32 * ks + 8 * g + j;
                fr[j] = (short)f2bf(W2[(size_t)k * HDIM + mb + 16 * t + n]);
            }
            a2f[t][ks] = fr;
        }
    // W3^T frags — FULL K in every wave (redundant L3 kills barrier B3 + reduce)
    short8 a3f[8];
#pragma unroll
    for (int ks = 0; ks < 8; ++ks) {
        short8 fr;
#pragma unroll
        for (int j = 0; j < 8; ++j) {
            int k = 32 * ks + 8 * g + j;
            fr[j] = (n < NDOF) ? (short)f2bf(W3[k * NDOF + n]) : (short)0;
        }
        a3f[ks] = fr;
    }
    f32x4 b2v[2];
#pragma unroll
    for (int t = 0; t < 2; ++t) {
        int m = mb + 16 * t + 4 * g;
        f32x4 tv; tv[0] = b2[m]; tv[1] = b2[m + 1]; tv[2] = b2[m + 2]; tv[3] = b2[m + 3];
        b2v[t] = tv;
    }
    f32x4 b3v;
#pragma unroll
    for (int r = 0; r < 4; ++r) {
        int m = 4 * g + r;
        b3v[r] = (m < NDOF) ? b3[m] : 0.0f;
    }

    // ---------------- state: lane (g,n) owns dofs d = 4g+r (g<2); matches C-layout
    f32x4 q, v, a;
    const float* sp = st0 + (size_t)(b0 + n) * 14;
#pragma unroll
    for (int r = 0; r < 4; ++r) {
        int d = 4 * g + r;
        bool val = (g < 2) && (d < NDOF);
        q[r] = val ? sp[d] : 0.0f;
        v[r] = val ? sp[7 + d] : 0.0f;
        a[r] = 0.0f;
    }
    float tn[8];
#pragma unroll
    for (int d = 0; d < 8; ++d) tn[d] = 0.0f;

    const float* tqb = tq + (size_t)(b0 + n) * (SEQ * NDOF);
    auto pf_tau = [&](int idx) {
        if (g == 2) {
            const float* tp = tqb + (size_t)idx * NDOF;
#pragma unroll
            for (int d = 0; d < 7; ++d) tn[d] = tp[d];
        }
    };

    short* xw = &xbuf[w * 640];

    // per-wave x strip write: g0 -> k0..3,k8..11 ; g1 -> k4..7,k12..15 ; g2 -> tau
    auto write_x = [&](f32x4 qn, f32x4 vp) {
        float lo_a = (g == 2) ? tn[0] : qn[0];
        float hi_a = (g == 2) ? tn[1] : qn[1];
        float lo_b = (g == 2) ? tn[2] : qn[2];
        float hi_b = (g == 2) ? tn[3] : ((g == 1) ? 1.0f : qn[3]);   // bias at k==7
        float lo_c = (g == 2) ? tn[4] : vp[0];
        float hi_c = (g == 2) ? tn[5] : vp[1];
        float lo_d = (g == 2) ? tn[6] : vp[2];
        float hi_d = (g == 2) ? 0.0f  : vp[3];                        // g1 vp[3]==0
        if (g < 3) {
            int off1 = (g == 2) ? 16 : 4 * g;
            int off2 = off1 + ((g == 2) ? 4 : 8);
            uint2v w1v, w2v;
            w1v[0] = cvt_pk_bf16(lo_a, hi_a); w1v[1] = cvt_pk_bf16(lo_b, hi_b);
            w2v[0] = cvt_pk_bf16(lo_c, hi_c); w2v[1] = cvt_pk_bf16(lo_d, hi_d);
            *(uint2v*)&xw[n * 40 + off1] = w1v;
            *(uint2v*)&xw[n * 40 + off2] = w2v;
        }
    };

    auto accel = [&]() -> f32x4 {
        const f32x4 cz = {0.0f, 0.0f, 0.0f, 0.0f};
        // L1 (intra-wave LDS: lgkmcnt orders write_x -> this read, no barrier)
        short8 xf = *(const short8*)&xw[n * 40 + 8 * g];
        f32x4 c1a = __builtin_amdgcn_mfma_f32_16x16x32_bf16(a1f[0], xf, cz, 0, 0, 0);
        f32x4 c1b = __builtin_amdgcn_mfma_f32_16x16x32_bf16(a1f[1], xf, cz, 0, 0, 0);
        {
            uint2v p;
            p[0] = cvt_pk_bf16(silu(c1a[0]), silu(c1a[1]));
            p[1] = cvt_pk_bf16(silu(c1a[2]), silu(c1a[3]));
            *(uint2v*)&h1b[n * 264 + mb + 4 * g] = p;
            p[0] = cvt_pk_bf16(silu(c1b[0]), silu(c1b[1]));
            p[1] = cvt_pk_bf16(silu(c1b[2]), silu(c1b[3]));
            *(uint2v*)&h1b[n * 264 + mb + 16 + 4 * g] = p;
        }
        __syncthreads();   // B1

        // L2
        f32x4 c2a = b2v[0], c2b = b2v[1];
#pragma unroll
        for (int ks = 0; ks < 8; ++ks) {
            short8 bfr = *(const short8*)&h1b[n * 264 + 32 * ks + 8 * g];
            c2a = __builtin_amdgcn_mfma_f32_16x16x32_bf16(a2f[0][ks], bfr, c2a, 0, 0, 0);
            c2b = __builtin_amdgcn_mfma_f32_16x16x32_bf16(a2f[1][ks], bfr, c2b, 0, 0, 0);
        }
        {
            uint2v p;
            p[0] = cvt_pk_bf16(silu(c2a[0]), silu(c2a[1]));
            p[1] = cvt_pk_bf16(silu(c2a[2]), silu(c2a[3]));
            *(uint2v*)&h2b[n * 264 + mb + 4 * g] = p;
            p[0] = cvt_pk_bf16(silu(c2b[0]), silu(c2b[1]));
            p[1] = cvt_pk_bf16(silu(c2b[2]), silu(c2b[3]));
            *(uint2v*)&h2b[n * 264 + mb + 16 + 4 * g] = p;
        }
        __syncthreads();   // B2

        // L3: every wave, full K=256 -> each lane gets exactly its own dofs
        f32x4 c3 = b3v;
#pragma unroll
        for (int ks = 0; ks < 8; ++ks) {
            short8 pfr = *(const short8*)&h2b[n * 264 + 32 * ks + 8 * g];
            c3 = __builtin_amdgcn_mfma_f32_16x16x32_bf16(a3f[ks], pfr, c3, 0, 0, 0);
        }
        return c3;
    };

    __syncthreads();   // init (xbuf zeros) visible

    // ---------------- prologue: a0 = accel(x0), tau idx 0 -------------------------
    pf_tau(0);
    write_x(q, v);
    {
        float tt = 1.0f * DTF;
        int ns = (int)floorf(tt / DTF);
        if (ns > SEQ - 1) ns = SEQ - 1;
        pf_tau(ns);
    }
    a = accel();

    // ---------------- 256 Verlet steps --------------------------------------------
    float* op = out + (size_t)(b0 + n) * SEQ * 14;

#pragma unroll 1
    for (int i = 0; i < SEQ; ++i) {
        f32x4 qn, vp;
#pragma unroll
        for (int r = 0; r < 4; ++r) {
            qn[r] = q[r] + v[r] * DTF + a[r] * (0.5f * DTF * DTF);
            vp[r] = v[r] + a[r] * DTF;
        }

        write_x(qn, vp);

        // prefetch tau for next step (exact formula from passing rounds)
        {
            float tt = (float)(i + 2) * DTF;
            int ns = (int)floorf(tt / DTF);
            if (ns > SEQ - 1) ns = SEQ - 1;
            pf_tau(ns);
        }

        f32x4 an = accel();

#pragma unroll
        for (int r = 0; r < 4; ++r)
            v[r] = v[r] + (a[r] + an[r]) * (0.5f * DTF);
        q = qn;
        a = an;

        if (w == 0 && g == 0) {
            float* o = op + (size_t)i * 14;
            *(f32x4*)(o)     = q;
            *(f32x4*)(o + 7) = v;
        } else if (w == 0 && g == 1) {
            float* o = op + (size_t)i * 14;
            o[4]  = q[0]; o[5]  = q[1]; o[6]  = q[2];
            o[11] = v[0]; o[12] = v[1]; o[13] = v[2];
        }
    }
}

extern "C" void kernel_launch(void* const* d_in, const int* in_sizes, int n_in,
                              void* d_out, int out_size, void* d_ws, size_t ws_size,
                              hipStream_t stream) {
    (void)in_sizes; (void)n_in; (void)d_ws; (void)ws_size; (void)out_size;
    const float* st0 = (const float*)d_in[0];
    const float* tq  = (const float*)d_in[1];
    const float* W1  = (const float*)d_in[2];
    const float* b1  = (const float*)d_in[3];
    const float* W2  = (const float*)d_in[4];
    const float* b2  = (const float*)d_in[5];
    const float* W3  = (const float*)d_in[6];
    const float* b3  = (const float*)d_in[7];

    NeuralODE_kernel<<<dim3(B_TOT / ROWS), dim3(512), 0, stream>>>(
        st0, tq, W1, b1, W2, b2, W3, b3, (float*)d_out);
}

// Round 5
// 383.093 us; speedup vs baseline: 1.0475x; 1.0475x over previous
//
#include <hip/hip_runtime.h>
#include <hip/hip_bf16.h>

typedef short    short8  __attribute__((ext_vector_type(8)));
typedef unsigned uint2v  __attribute__((ext_vector_type(2)));
typedef float    f32x4   __attribute__((ext_vector_type(4)));

#define B_TOT 4096
#define SEQ   256
#define NDOF  7
#define HDIM  256
#define ROWS  16
#define DTF   0.002f

// RNE float->bf16 (setup only)
static __device__ __forceinline__ unsigned short f2bf(float f) {
    union { float f; unsigned u; } u; u.f = f;
    unsigned x = u.u;
    unsigned r = (x + 0x7FFFu + ((x >> 16) & 1u)) >> 16;
    return (unsigned short)r;
}
static __device__ __forceinline__ unsigned cvt_pk_bf16(float lo, float hi) {
    unsigned r;
    asm("v_cvt_pk_bf16_f32 %0, %1, %2" : "=v"(r) : "v"(lo), "v"(hi));
    return r;
}
static __device__ __forceinline__ float silu(float p) {
    return p * __builtin_amdgcn_rcpf(1.0f + __expf(-p));
}

__global__ __launch_bounds__(512, 2)
void NeuralODE_kernel(const float* __restrict__ st0, const float* __restrict__ tq,
                      const float* __restrict__ W1,  const float* __restrict__ b1,
                      const float* __restrict__ W2,  const float* __restrict__ b2,
                      const float* __restrict__ W3,  const float* __restrict__ b3,
                      float* __restrict__ out)
{
    __shared__ __align__(16) short h1b[16 * 264];      // h1 exchange (16 rows x 256 + pad)
    __shared__ __align__(16) short xstrip[8 * 16 * 40]; // per-wave x strips
    __shared__ __align__(16) short hstrip[8 * 16 * 40]; // per-wave h2 transpose strips
    __shared__ __align__(16) float red[8][16][12];      // L3 partials (stride 12)

    const int tid  = threadIdx.x;
    const int w    = tid >> 6;          // 8 waves
    const int lane = tid & 63;
    const int g    = lane >> 4;
    const int n    = lane & 15;
    const int b0   = blockIdx.x * ROWS;
    const int mb   = 32 * w;

    // ---------------- init: zero x strips (k24..39 stay zero forever) ------------
    for (int i = tid; i < 8 * 16 * 40; i += 512) xstrip[i] = 0;

    // ---------------- weight fragments (transposed GEMM; b1 folded at k==7) ------
    short8 a1f[2];
#pragma unroll
    for (int t = 0; t < 2; ++t) {
        short8 fr;
#pragma unroll
        for (int j = 0; j < 8; ++j) {
            int k = 8 * g + j;   // x: 0-6=q, 7=1(bias), 8-14=v, 15=0, 16-22=tau, 23+=0
            int m = mb + 16 * t + n;
            float v;
            if (k < 7)        v = W1[k * HDIM + m];
            else if (k == 7)  v = b1[m];
            else if (k < 15)  v = W1[(k - 1) * HDIM + m];
            else if (k == 15) v = 0.0f;
            else if (k < 23)  v = W1[(k - 2) * HDIM + m];
            else              v = 0.0f;
            fr[j] = (short)f2bf(v);
        }
        a1f[t] = fr;
    }
    short8 a2f[2][8];
#pragma unroll
    for (int t = 0; t < 2; ++t)
#pragma unroll
        for (int ks = 0; ks < 8; ++ks) {
            short8 fr;
#pragma unroll
            for (int j = 0; j < 8; ++j) {
                int k = 32 * ks + 8 * g + j;
                fr[j] = (short)f2bf(W2[(size_t)k * HDIM + mb + 16 * t + n]);
            }
            a2f[t][ks] = fr;
        }
    // W3^T fragment for THIS wave's k-slice [32w, 32w+32) (fused L3)
    short8 a3f;
#pragma unroll
    for (int j = 0; j < 8; ++j) {
        int k = mb + 8 * g + j;
        a3f[j] = (n < NDOF) ? (short)f2bf(W3[k * NDOF + n]) : (short)0;
    }
    f32x4 b2v[2];
#pragma unroll
    for (int t = 0; t < 2; ++t) {
        int m = mb + 16 * t + 4 * g;
        f32x4 tv; tv[0] = b2[m]; tv[1] = b2[m + 1]; tv[2] = b2[m + 2]; tv[3] = b2[m + 3];
        b2v[t] = tv;
    }
    f32x4 b3v;
#pragma unroll
    for (int r = 0; r < 4; ++r) {
        int m = 4 * g + r;
        b3v[r] = (m < NDOF) ? b3[m] : 0.0f;
    }

    // ---------------- state: lane (g,n), g<2, owns dofs d = 4g+r (= C layout) ----
    f32x4 q, v, a;
    const float* sp = st0 + (size_t)(b0 + n) * 14;
#pragma unroll
    for (int r = 0; r < 4; ++r) {
        int d = 4 * g + r;
        bool val = (g < 2) && (d < NDOF);
        q[r] = val ? sp[d] : 0.0f;
        v[r] = val ? sp[7 + d] : 0.0f;
        a[r] = 0.0f;
    }
    float tn[8];
#pragma unroll
    for (int d = 0; d < 8; ++d) tn[d] = 0.0f;

    const float* tqb = tq + (size_t)(b0 + n) * (SEQ * NDOF);
    auto pf_tau = [&](int idx) {
        if (g == 2) {
            const float* tp = tqb + (size_t)idx * NDOF;
#pragma unroll
            for (int d = 0; d < 7; ++d) tn[d] = tp[d];
        }
    };

    // per-(wave,row) LDS bases, hoisted
    short* xw  = &xstrip[w * 640 + n * 40];
    short* hw  = &hstrip[w * 640 + n * 40];
    short* h1w = &h1b[n * 264 + mb];          // this wave's h1 write base
    const short* h1r = &h1b[n * 264 + 8 * g]; // L2 B-read base

    // x strip write: g0 -> k0..3,8..11 ; g1 -> k4..7,12..15 ; g2 -> k16..23
    auto write_x = [&](f32x4 qn, f32x4 vp) {
        float lo_a = (g == 2) ? tn[0] : qn[0];
        float hi_a = (g == 2) ? tn[1] : qn[1];
        float lo_b = (g == 2) ? tn[2] : qn[2];
        float hi_b = (g == 2) ? tn[3] : ((g == 1) ? 1.0f : qn[3]);   // bias at k==7
        float lo_c = (g == 2) ? tn[4] : vp[0];
        float hi_c = (g == 2) ? tn[5] : vp[1];
        float lo_d = (g == 2) ? tn[6] : vp[2];
        float hi_d = (g == 2) ? 0.0f  : vp[3];
        if (g < 3) {
            int off1 = (g == 2) ? 16 : 4 * g;
            int off2 = off1 + ((g == 2) ? 4 : 8);
            uint2v w1v, w2v;
            w1v[0] = cvt_pk_bf16(lo_a, hi_a); w1v[1] = cvt_pk_bf16(lo_b, hi_b);
            w2v[0] = cvt_pk_bf16(lo_c, hi_c); w2v[1] = cvt_pk_bf16(lo_d, hi_d);
            *(uint2v*)&xw[off1] = w1v;
            *(uint2v*)&xw[off2] = w2v;
        }
    };

    auto accel = [&]() -> f32x4 {
        const f32x4 cz = {0.0f, 0.0f, 0.0f, 0.0f};
        // ---- L1 (intra-wave strip, no barrier) ----
        short8 xf = *(const short8*)&xw[8 * g];
        f32x4 c1a = __builtin_amdgcn_mfma_f32_16x16x32_bf16(a1f[0], xf, cz, 0, 0, 0);
        f32x4 c1b = __builtin_amdgcn_mfma_f32_16x16x32_bf16(a1f[1], xf, cz, 0, 0, 0);
        {
            uint2v p;
            p[0] = cvt_pk_bf16(silu(c1a[0]), silu(c1a[1]));
            p[1] = cvt_pk_bf16(silu(c1a[2]), silu(c1a[3]));
            *(uint2v*)&h1w[4 * g] = p;
            p[0] = cvt_pk_bf16(silu(c1b[0]), silu(c1b[1]));
            p[1] = cvt_pk_bf16(silu(c1b[2]), silu(c1b[3]));
            *(uint2v*)&h1w[16 + 4 * g] = p;
        }
        __syncthreads();   // B1: h1 complete

        // ---- L2 ----
        f32x4 c2a = b2v[0], c2b = b2v[1];
#pragma unroll
        for (int ks = 0; ks < 8; ++ks) {
            short8 bfr = *(const short8*)&h1r[32 * ks];
            c2a = __builtin_amdgcn_mfma_f32_16x16x32_bf16(a2f[0][ks], bfr, c2a, 0, 0, 0);
            c2b = __builtin_amdgcn_mfma_f32_16x16x32_bf16(a2f[1][ks], bfr, c2b, 0, 0, 0);
        }

        // ---- fused L3: silu -> in-wave transpose via private strip -> 1 MFMA ----
        {
            uint2v pa, pb;
            pa[0] = cvt_pk_bf16(silu(c2a[0]), silu(c2a[1]));
            pa[1] = cvt_pk_bf16(silu(c2a[2]), silu(c2a[3]));
            pb[0] = cvt_pk_bf16(silu(c2b[0]), silu(c2b[1]));
            pb[1] = cvt_pk_bf16(silu(c2b[2]), silu(c2b[3]));
            *(uint2v*)&hw[4 * g]      = pa;   // x = 4g..4g+3   (m = mb+x)
            *(uint2v*)&hw[16 + 4 * g] = pb;   // x = 16+4g..+3
        }
        short8 pfr = *(const short8*)&hw[8 * g];   // B-layout: k_local = 8g+j
        f32x4 c3 = __builtin_amdgcn_mfma_f32_16x16x32_bf16(
                       a3f, pfr, (w == 0) ? b3v : cz, 0, 0, 0);
        if (g < 2) *(f32x4*)&red[w][n][4 * g] = c3;
        __syncthreads();   // B2: partials complete

        // ---- reduce 8 partials (g<2 lanes only; C layout == state layout) ----
        f32x4 an = cz;
        if (g < 2) {
            const float* rb = &red[0][n][4 * g];
            f32x4 s0 = *(const f32x4*)(rb)        + *(const f32x4*)(rb + 192);
            f32x4 s1 = *(const f32x4*)(rb + 384)  + *(const f32x4*)(rb + 576);
            f32x4 s2 = *(const f32x4*)(rb + 768)  + *(const f32x4*)(rb + 960);
            f32x4 s3 = *(const f32x4*)(rb + 1152) + *(const f32x4*)(rb + 1344);
            an = (s0 + s1) + (s2 + s3);
        }
        return an;
    };

    __syncthreads();   // init (xstrip zeros) visible

    // ---------------- prologue: a0 = accel(x0), tau idx 0 -------------------------
    pf_tau(0);
    write_x(q, v);
    {
        float tt = 1.0f * DTF;
        int ns = (int)floorf(tt / DTF);
        if (ns > SEQ - 1) ns = SEQ - 1;
        pf_tau(ns);
    }
    a = accel();

    // ---------------- 256 Verlet steps --------------------------------------------
    float* op = out + (size_t)(b0 + n) * SEQ * 14;

#pragma unroll 1
    for (int i = 0; i < SEQ; ++i) {
        f32x4 qn, vp;
#pragma unroll
        for (int r = 0; r < 4; ++r) {
            qn[r] = q[r] + v[r] * DTF + a[r] * (0.5f * DTF * DTF);
            vp[r] = v[r] + a[r] * DTF;
        }

        write_x(qn, vp);

        // prefetch tau for next step (exact formula from passing rounds)
        {
            float tt = (float)(i + 2) * DTF;
            int ns = (int)floorf(tt / DTF);
            if (ns > SEQ - 1) ns = SEQ - 1;
            pf_tau(ns);
        }

        f32x4 an = accel();

#pragma unroll
        for (int r = 0; r < 4; ++r)
            v[r] = v[r] + (a[r] + an[r]) * (0.5f * DTF);
        q = qn;
        a = an;

        if (w == 0 && g == 0) {
            float* o = op + (size_t)i * 14;
            *(f32x4*)(o)     = q;
            *(f32x4*)(o + 7) = v;
        } else if (w == 0 && g == 1) {
            float* o = op + (size_t)i * 14;
            o[4]  = q[0]; o[5]  = q[1]; o[6]  = q[2];
            o[11] = v[0]; o[12] = v[1]; o[13] = v[2];
        }
    }
}

extern "C" void kernel_launch(void* const* d_in, const int* in_sizes, int n_in,
                              void* d_out, int out_size, void* d_ws, size_t ws_size,
                              hipStream_t stream) {
    (void)in_sizes; (void)n_in; (void)d_ws; (void)ws_size; (void)out_size;
    const float* st0 = (const float*)d_in[0];
    const float* tq  = (const float*)d_in[1];
    const float* W1  = (const float*)d_in[2];
    const float* b1  = (const float*)d_in[3];
    const float* W2  = (const float*)d_in[4];
    const float* b2  = (const float*)d_in[5];
    const float* W3  = (const float*)d_in[6];
    const float* b3  = (const float*)d_in[7];

    NeuralODE_kernel<<<dim3(B_TOT / ROWS), dim3(512), 0, stream>>>(
        st0, tq, W1, b1, W2, b2, W3, b3, (float*)d_out);
}